// Round 11
// baseline (283.721 us; speedup 1.0000x reference)
//
#include <hip/hip_runtime.h>

#define Bz 32
#define Nn 510
#define Dd 64
#define Hh 4
#define HD_ 256
#define Kpad 512
#define ALPHA_ 0.1f
#define LNEPS 1e-5f
#define SLOPE 0.01f
#define NEG_INF -3.0e38f

typedef __attribute__((ext_vector_type(8))) short short8;
typedef __attribute__((ext_vector_type(4))) float floatx4;

__device__ inline float wredsum(float v) {
  #pragma unroll
  for (int off = 32; off; off >>= 1) v += __shfl_xor(v, off, 64);
  return v;
}
__device__ inline float wredmax(float v) {
  #pragma unroll
  for (int off = 32; off; off >>= 1) v = fmaxf(v, __shfl_xor(v, off, 64));
  return v;
}
__device__ inline unsigned short f2bf(float f) {
  unsigned int u = __float_as_uint(f);
  unsigned int r = (u + 0x7fffu + ((u >> 16) & 1u)) >> 16;
  return (unsigned short)r;
}

// K1 v3 (round-8 verbatim, verified): one head per block.
__global__ __launch_bounds__(256) void k1_xt(const float* __restrict__ x,
                                             const float* __restrict__ W,
                                             const float* __restrict__ attw,
                                             unsigned short* __restrict__ xtT,
                                             float* __restrict__ si,
                                             float* __restrict__ sj) {
  __shared__ float Wl[64][68];
  __shared__ float xr[32][68];
  __shared__ unsigned short st[64 * 33];
  const int t = threadIdx.x;
  const int rt = blockIdx.x;
  const int b = blockIdx.y;
  const int ch = blockIdx.z;
  #pragma unroll
  for (int k = 0; k < 4; k++) {
    int f = t + k * 256;
    int kr = f >> 4;
    int c = (f & 15) * 4;
    *(float4*)&Wl[kr][c] = *(const float4*)&W[kr * HD_ + ch * 64 + c];
  }
  #pragma unroll
  for (int k = 0; k < 2; k++) {
    int f = t + k * 256;
    int r = f >> 4;
    int c = (f & 15) * 4;
    int row = rt * 32 + r;
    float4 v = make_float4(0.f, 0.f, 0.f, 0.f);
    if (row < Nn) v = *(const float4*)&x[(b * Nn + row) * Dd + c];
    *(float4*)&xr[r][c] = v;
  }
  __syncthreads();
  const int tg = t >> 4;
  const int tc = t & 15;
  const int rb = tg * 2, c0 = tc * 4;
  float acc[2][4] = {};
  #pragma unroll
  for (int k4 = 0; k4 < 16; k4++) {
    float4 xv0 = *(float4*)&xr[rb][k4 * 4];
    float4 xv1 = *(float4*)&xr[rb + 1][k4 * 4];
    #pragma unroll
    for (int kk = 0; kk < 4; kk++) {
      float4 wv = *(float4*)&Wl[k4 * 4 + kk][c0];
      float xs0 = (&xv0.x)[kk];
      float xs1 = (&xv1.x)[kk];
      acc[0][0] = fmaf(xs0, wv.x, acc[0][0]);
      acc[0][1] = fmaf(xs0, wv.y, acc[0][1]);
      acc[0][2] = fmaf(xs0, wv.z, acc[0][2]);
      acc[0][3] = fmaf(xs0, wv.w, acc[0][3]);
      acc[1][0] = fmaf(xs1, wv.x, acc[1][0]);
      acc[1][1] = fmaf(xs1, wv.y, acc[1][1]);
      acc[1][2] = fmaf(xs1, wv.z, acc[1][2]);
      acc[1][3] = fmaf(xs1, wv.w, acc[1][3]);
    }
  }
  #pragma unroll
  for (int cc = 0; cc < 4; cc++) {
    #pragma unroll
    for (int r = 0; r < 2; r++) {
      st[(c0 + cc) * 33 + rb + r] = f2bf(acc[r][cc]);
    }
  }
  float w1v[4], w2v[4];
  #pragma unroll
  for (int cc = 0; cc < 4; cc++) {
    w1v[cc] = attw[ch * 128 + c0 + cc];
    w2v[cc] = attw[ch * 128 + 64 + c0 + cc];
  }
  #pragma unroll
  for (int r = 0; r < 2; r++) {
    float p1 = acc[r][0] * w1v[0] + acc[r][1] * w1v[1] +
               acc[r][2] * w1v[2] + acc[r][3] * w1v[3];
    float p2 = acc[r][0] * w2v[0] + acc[r][1] * w2v[1] +
               acc[r][2] * w2v[2] + acc[r][3] * w2v[3];
    #pragma unroll
    for (int off = 1; off <= 8; off <<= 1) {
      p1 += __shfl_xor(p1, off, 64);
      p2 += __shfl_xor(p2, off, 64);
    }
    if (tc == 0) {
      int row = rt * 32 + rb + r;
      if (row < Nn) {
        si[(b * 4 + ch) * Nn + row] = p1;
        sj[(b * 4 + ch) * Nn + row] = p2;
      }
    }
  }
  __syncthreads();
  if (t < 64) {
    unsigned short* dst = &xtT[((size_t)(b * 4 + ch) * 64 + t) * Kpad + rt * 32];
    #pragma unroll
    for (int q = 0; q < 4; q++) {
      short8 v;
      #pragma unroll
      for (int k = 0; k < 8; k++) v[k] = (short)st[t * 33 + q * 8 + k];
      *(short8*)&dst[q * 8] = v;
    }
  }
}

// K2a (round-8 verbatim, verified): causal-channel conv + bias, once.
__global__ __launch_bounds__(256) void k2a_cconv(const float* __restrict__ causal,
                                                 const float* __restrict__ convw,
                                                 const float* __restrict__ convb,
                                                 float* __restrict__ ccv) {
  const int i = blockIdx.x;
  const int t = threadIdx.x;
  #pragma unroll
  for (int qq = 0; qq < 2; qq++) {
    const int j = t + qq * 256;
    float tap[9];
    #pragma unroll
    for (int r3 = 0; r3 < 3; r3++) {
      int ii = i - 1 + r3;
      #pragma unroll
      for (int c3 = 0; c3 < 3; c3++) {
        int jj = j - 1 + c3;
        tap[r3 * 3 + c3] = (ii >= 0 && ii < Nn && jj >= 0 && jj < Nn)
                               ? causal[ii * Nn + jj] : 0.f;
      }
    }
    #pragma unroll
    for (int h = 0; h < 4; h++) {
      float acc = convb[h];
      #pragma unroll
      for (int q = 0; q < 9; q++) acc = fmaf(convw[h * 18 + 9 + q], tap[q], acc);
      ccv[((size_t)h * Nn + i) * 512 + j] = acc;
    }
  }
}

// K2 v2 (round-8 verbatim) + optional A16 bf16 shadow write (a16 != null).
// A16[b][h][i][512] = f2bf(A row); pad j>=Nn is 0 naturally (exp(-inf)=0).
__global__ __launch_bounds__(256) void k2_attn(const float* __restrict__ si,
                                               const float* __restrict__ sj,
                                               const float* __restrict__ ccv,
                                               const float* __restrict__ convw,
                                               float* __restrict__ A,
                                               unsigned short* __restrict__ a16) {
  __shared__ float am_t[10 * 8 * 68];   // [row r][e=j&7][c=(j>>3)+1]
  __shared__ float sjl[4 * 8 * 68];     // [h][e][c]
  __shared__ float sil[4][12];
  __shared__ float cwl[4][9];           // am-channel conv weights
  const int t = threadIdx.x;
  const int i0 = blockIdx.x * 8;
  const int b = blockIdx.y;
  if (t < 36) cwl[t / 9][t % 9] = convw[(t / 9) * 18 + (t % 9)];
  if (t < 40) {
    int h = t / 10, r = t % 10;
    int iq = i0 + r - 1;
    sil[h][r] = (iq >= 0 && iq < Nn) ? si[(b * 4 + h) * Nn + iq] : 0.f;
  }
  if (t >= 64 && t < 224) {
    int q = t - 64;
    int r = q >> 4, rem = q & 15;
    int e = rem >> 1, side = rem & 1;
    am_t[(r * 8 + e) * 68 + side * 65] = 0.f;
  }
  for (int f = t; f < 2048; f += 256) {
    int h = f >> 9, j = f & 511;
    float v = (j < Nn) ? sj[(b * 4 + h) * Nn + j] : 0.f;
    sjl[(h * 8 + (j & 7)) * 68 + (j >> 3) + 1] = v;
  }
  __syncthreads();
  for (int f = t; f < 5120; f += 256) {
    int r = f >> 9, j = f & 511;
    int iq = i0 + r - 1;
    float am = 0.f;
    if (iq >= 0 && iq < Nn && j < Nn) {
      float s = 0.f;
      #pragma unroll
      for (int h = 0; h < 4; h++) {
        float e2 = sil[h][r] + sjl[(h * 8 + (j & 7)) * 68 + (j >> 3) + 1];
        s += (e2 >= 0.f) ? e2 : SLOPE * e2;
      }
      am = 0.25f * s;
    }
    am_t[(r * 8 + (j & 7)) * 68 + (j >> 3) + 1] = am;
  }
  __syncthreads();
  const int w = t >> 6, L = t & 63;
  const int j0 = L * 8;
  #pragma unroll
  for (int qq = 0; qq < 2; qq++) {
    const int il = w * 2 + qq;
    const int i = i0 + il;
    if (i >= Nn) continue;
    float conv[4][8];
    #pragma unroll
    for (int h = 0; h < 4; h++) {
      const float* cp = &ccv[((size_t)h * Nn + i) * 512 + j0];
      float4 c0 = *(const float4*)&cp[0];
      float4 c1 = *(const float4*)&cp[4];
      conv[h][0] = c0.x; conv[h][1] = c0.y; conv[h][2] = c0.z; conv[h][3] = c0.w;
      conv[h][4] = c1.x; conv[h][5] = c1.y; conv[h][6] = c1.z; conv[h][7] = c1.w;
    }
    #pragma unroll
    for (int r3 = 0; r3 < 3; r3++) {
      const float* ba = &am_t[((il + r3) * 8) * 68];
      float a[10];
      a[0] = ba[7 * 68 + L];
      #pragma unroll
      for (int e = 0; e < 8; e++) a[1 + e] = ba[e * 68 + L + 1];
      a[9] = ba[0 * 68 + L + 2];
      #pragma unroll
      for (int h = 0; h < 4; h++) {
        float w0 = cwl[h][r3 * 3], w1 = cwl[h][r3 * 3 + 1], w2 = cwl[h][r3 * 3 + 2];
        #pragma unroll
        for (int e = 0; e < 8; e++) {
          float cv = conv[h][e];
          cv = fmaf(w0, a[e], cv);
          cv = fmaf(w1, a[e + 1], cv);
          cv = fmaf(w2, a[e + 2], cv);
          conv[h][e] = cv;
        }
      }
    }
    #pragma unroll
    for (int h = 0; h < 4; h++) {
      const float sih = sil[h][il + 1];
      float v[8];
      float mx = NEG_INF;
      #pragma unroll
      for (int e = 0; e < 8; e++) {
        float ee = sih + sjl[(h * 8 + e) * 68 + L + 1];
        float l = (ee >= 0.f) ? ee : SLOPE * ee;
        float val = ALPHA_ * l + (1.0f - ALPHA_) * conv[h][e];
        v[e] = (j0 + e < Nn) ? val : NEG_INF;
        mx = fmaxf(mx, v[e]);
      }
      mx = wredmax(mx);
      float p[8], s = 0.f;
      #pragma unroll
      for (int e = 0; e < 8; e++) {
        p[e] = __expf(v[e] - mx);
        s += p[e];
      }
      s = wredsum(s);
      const float inv = 1.f / s;
      #pragma unroll
      for (int e = 0; e < 8; e++) p[e] *= inv;
      float* Ar = &A[((size_t)(b * 4 + h) * Nn + i) * Nn + j0];
      *(float4*)&Ar[0] = make_float4(p[0], p[1], p[2], p[3]);
      if (L < 63) {
        *(float4*)&Ar[4] = make_float4(p[4], p[5], p[6], p[7]);
      } else {
        *(float2*)&Ar[4] = make_float2(p[4], p[5]);
      }
      if (a16) {
        short8 pv;
        #pragma unroll
        for (int e = 0; e < 8; e++) pv[e] = (short)f2bf(p[e]);
        *(short8*)&a16[(((size_t)(b * 4 + h) * 512 + i) * 512) + j0] = pv;
      }
    }
  }
}

// K3 v5: A-fragments loaded DIRECTLY from the bf16 shadow A16 (no LDS
// staging, no conversions, zero K-loop barriers). 16-row tile = 16 KB ->
// L1-resident, so the 4-wave read redundancy is cached. Accumulation order
// identical to v4 -> y bit-identical.
__global__ __launch_bounds__(256) void k3_a16(const unsigned short* __restrict__ A16,
                                              const unsigned short* __restrict__ xtT,
                                              const float* __restrict__ x,
                                              const float* __restrict__ fcgw,
                                              const float* __restrict__ fcgb,
                                              const float* __restrict__ lng,
                                              const float* __restrict__ lnb,
                                              float* __restrict__ y) {
  __shared__ float ol[16][64];
  __shared__ float gl[2][128];
  const int t = threadIdx.x;
  const int n0 = blockIdx.x * 16;
  const int b = blockIdx.y;
  const int w = t >> 6, L = t & 63;
  const int quad = L >> 4, l16 = L & 15;
  const int wc = w * 16;
  const int arow = (n0 + l16 < Nn) ? (n0 + l16) : (Nn - 1);  // clamp; rows>=Nn discarded
  floatx4 acc = {0.f, 0.f, 0.f, 0.f};
  #pragma unroll
  for (int h = 0; h < 4; h++) {
    const unsigned short* Ar = &A16[(((size_t)(b * 4 + h) * 512) + arow) * 512];
    const unsigned short* Xr = &xtT[((size_t)(b * 4 + h) * 64 + wc + l16) * Kpad];
    #pragma unroll
    for (int kt = 0; kt < 8; kt++) {
      const int m = kt * 64;
      short8 af0 = *(const short8*)&Ar[m + quad * 8];
      short8 bf0 = *(const short8*)&Xr[m + quad * 8];
      acc = __builtin_amdgcn_mfma_f32_16x16x32_bf16(af0, bf0, acc, 0, 0, 0);
      short8 af1 = *(const short8*)&Ar[m + 32 + quad * 8];
      short8 bf1 = *(const short8*)&Xr[m + 32 + quad * 8];
      acc = __builtin_amdgcn_mfma_f32_16x16x32_bf16(af1, bf1, acc, 0, 0, 0);
    }
  }
  #pragma unroll
  for (int reg = 0; reg < 4; reg++) {
    ol[quad * 4 + reg][wc + l16] = 0.25f * acc[reg];
  }
  __syncthreads();
  const int kk = t & 127;
  const int rg = t >> 7;
  for (int it = 0; it < 8; it++) {
    const int r = it * 2 + rg;
    const int row = n0 + r;
    float g = fcgb[kk];
    #pragma unroll
    for (int d = 0; d < 64; d++) g = fmaf(ol[r][d], fcgw[d * 128 + kk], g);
    gl[rg][kk] = g;
    __syncthreads();
    if (kk < 64 && row < Nn) {
      float a = gl[rg][kk];
      float bb = gl[rg][kk + 64];
      float glu = a / (1.f + __expf(-bb));
      float yv = glu + x[(b * Nn + row) * Dd + kk];
      float mu = wredsum(yv) * (1.f / 64.f);
      float dv = yv - mu;
      float var = wredsum(dv * dv) * (1.f / 64.f);
      float o = dv * rsqrtf(var + LNEPS) * lng[kk] + lnb[kk];
      y[(b * Nn + row) * Dd + kk] = o;
    }
    __syncthreads();
  }
}

// K3 v4 (round-8 verbatim): fallback when ws is too small for A16.
__global__ __launch_bounds__(256) void k3_out(const float* __restrict__ A,
                                              const unsigned short* __restrict__ xtT,
                                              const float* __restrict__ x,
                                              const float* __restrict__ fcgw,
                                              const float* __restrict__ fcgb,
                                              const float* __restrict__ lng,
                                              const float* __restrict__ lnb,
                                              float* __restrict__ y) {
  __shared__ unsigned short Asub[3][16 * 72];
  __shared__ float ol[16][64];
  __shared__ float gl[2][128];
  const int t = threadIdx.x;
  const int n0 = blockIdx.x * 16;
  const int b = blockIdx.y;
  const int w = t >> 6, L = t & 63;
  const int quad = L >> 4, l16 = L & 15;
  const int wc = w * 16;
  const int ar = t >> 4;
  const int amc = (t & 15) * 4;
  const int nrow = n0 + ar;
  floatx4 acc = {0.f, 0.f, 0.f, 0.f};

  auto loadA = [&](int p, float* av) {
    const int h = p >> 3;
    const int m = (p & 7) * 64 + amc;
    av[0] = av[1] = av[2] = av[3] = 0.f;
    if (nrow < Nn) {
      const float* src = &A[((size_t)(b * 4 + h) * Nn + nrow) * Nn + m];
      if (m + 3 < Nn) {
        float2 v0 = *(const float2*)&src[0];
        float2 v1 = *(const float2*)&src[2];
        av[0] = v0.x; av[1] = v0.y; av[2] = v1.x; av[3] = v1.y;
      } else {
        int lim = Nn - m;
        #pragma unroll
        for (int q = 0; q < 4; q++) if (q < lim) av[q] = src[q];
      }
    }
  };
  auto writeA = [&](int p, const float* av) {
    ushort4 u;
    u.x = f2bf(av[0]); u.y = f2bf(av[1]);
    u.z = f2bf(av[2]); u.w = f2bf(av[3]);
    *(ushort4*)&Asub[p % 3][ar * 72 + amc] = u;
  };

  float rvA[4], rvB[4];
  loadA(0, rvA);
  loadA(1, rvB);
  writeA(0, rvA);
  __syncthreads();
  #pragma unroll
  for (int p = 0; p < 32; p++) {
    if (p + 2 < 32) loadA(p + 2, (p & 1) ? rvB : rvA);
    if (p + 1 < 32) writeA(p + 1, (p & 1) ? rvA : rvB);
    __syncthreads();
    const int h = p >> 3;
    const unsigned short* Xr =
        &xtT[((size_t)(b * 4 + h) * 64 + wc + l16) * Kpad + (p & 7) * 64];
    const unsigned short* Ab = &Asub[p % 3][l16 * 72];
    short8 af0 = *(const short8*)&Ab[quad * 8];
    short8 bf0 = *(const short8*)&Xr[quad * 8];
    acc = __builtin_amdgcn_mfma_f32_16x16x32_bf16(af0, bf0, acc, 0, 0, 0);
    short8 af1 = *(const short8*)&Ab[32 + quad * 8];
    short8 bf1 = *(const short8*)&Xr[32 + quad * 8];
    acc = __builtin_amdgcn_mfma_f32_16x16x32_bf16(af1, bf1, acc, 0, 0, 0);
  }

  __syncthreads();
  #pragma unroll
  for (int reg = 0; reg < 4; reg++) {
    ol[quad * 4 + reg][wc + l16] = 0.25f * acc[reg];
  }
  __syncthreads();
  const int kk = t & 127;
  const int rg = t >> 7;
  for (int it = 0; it < 8; it++) {
    const int r = it * 2 + rg;
    const int row = n0 + r;
    float g = fcgb[kk];
    #pragma unroll
    for (int d = 0; d < 64; d++) g = fmaf(ol[r][d], fcgw[d * 128 + kk], g);
    gl[rg][kk] = g;
    __syncthreads();
    if (kk < 64 && row < Nn) {
      float a = gl[rg][kk];
      float bb = gl[rg][kk + 64];
      float glu = a / (1.f + __expf(-bb));
      float yv = glu + x[(b * Nn + row) * Dd + kk];
      float mu = wredsum(yv) * (1.f / 64.f);
      float dv = yv - mu;
      float var = wredsum(dv * dv) * (1.f / 64.f);
      float o = dv * rsqrtf(var + LNEPS) * lng[kk] + lnb[kk];
      y[(b * Nn + row) * Dd + kk] = o;
    }
    __syncthreads();
  }
}

extern "C" void kernel_launch(void* const* d_in, const int* in_sizes, int n_in,
                              void* d_out, int out_size, void* d_ws, size_t ws_size,
                              hipStream_t stream) {
  const float* x      = (const float*)d_in[0];
  const float* causal = (const float*)d_in[1];
  const float* W      = (const float*)d_in[2];
  const float* attw   = (const float*)d_in[3];
  const float* convw  = (const float*)d_in[4];
  const float* convb  = (const float*)d_in[5];
  const float* fcgw   = (const float*)d_in[6];
  const float* fcgb   = (const float*)d_in[7];
  const float* lng    = (const float*)d_in[8];
  const float* lnb    = (const float*)d_in[9];

  float* ws = (float*)d_ws;
  float* si = ws;                                  // 65,280 floats
  float* sj = si + (size_t)Bz * Hh * Nn;           // 65,280 floats (+16 pad)
  unsigned short* xtT = (unsigned short*)(sj + (size_t)Bz * Hh * Nn + 16);
  // xtT ends at byte 8,910,912; ccv = 4*510*512 floats ends at 13,088,832.
  float* ccv = (float*)(xtT + (size_t)Bz * Hh * Dd * Kpad);

  const size_t base_bytes = 13088832;                        // used ws so far
  const size_t a16_bytes  = (size_t)Bz * Hh * 512 * 512 * 2; // 67,108,864
  const bool use16 = ws_size >= base_bytes + a16_bytes;
  unsigned short* a16 =
      use16 ? (unsigned short*)((char*)d_ws + base_bytes) : (unsigned short*)0;

  float* yout = (float*)d_out;                     // 32*510*64
  float* Aout = yout + (size_t)Bz * Nn * Dd;       // 32*4*510*510

  k2a_cconv<<<dim3(Nn), 256, 0, stream>>>(causal, convw, convb, ccv);
  k1_xt  <<<dim3(16, Bz, 4), 256, 0, stream>>>(x, W, attw, xtT, si, sj);
  k2_attn<<<dim3(64, Bz), 256, 0, stream>>>(si, sj, ccv, convw, Aout, a16);
  if (use16) {
    k3_a16<<<dim3(32, Bz), 256, 0, stream>>>(a16, xtT, x, fcgw, fcgb, lng, lnb, yout);
  } else {
    k3_out<<<dim3(32, Bz), 256, 0, stream>>>(Aout, xtT, x, fcgw, fcgb, lng, lnb, yout);
  }
}

// Round 12
// 265.965 us; speedup vs baseline: 1.0668x; 1.0668x over previous
//
#include <hip/hip_runtime.h>

#define Bz 32
#define Nn 510
#define Dd 64
#define Hh 4
#define HD_ 256
#define Kpad 512
#define ALPHA_ 0.1f
#define LNEPS 1e-5f
#define SLOPE 0.01f
#define NEG_INF -3.0e38f

typedef __attribute__((ext_vector_type(8))) short short8;
typedef __attribute__((ext_vector_type(4))) float floatx4;

__device__ inline float wredsum(float v) {
  #pragma unroll
  for (int off = 32; off; off >>= 1) v += __shfl_xor(v, off, 64);
  return v;
}
__device__ inline float wredmax(float v) {
  #pragma unroll
  for (int off = 32; off; off >>= 1) v = fmaxf(v, __shfl_xor(v, off, 64));
  return v;
}
__device__ inline unsigned short f2bf(float f) {
  unsigned int u = __float_as_uint(f);
  unsigned int r = (u + 0x7fffu + ((u >> 16) & 1u)) >> 16;
  return (unsigned short)r;
}

// K1 v3 (round-8 verbatim, verified): one head per block.
__global__ __launch_bounds__(256) void k1_xt(const float* __restrict__ x,
                                             const float* __restrict__ W,
                                             const float* __restrict__ attw,
                                             unsigned short* __restrict__ xtT,
                                             float* __restrict__ si,
                                             float* __restrict__ sj) {
  __shared__ float Wl[64][68];
  __shared__ float xr[32][68];
  __shared__ unsigned short st[64 * 33];
  const int t = threadIdx.x;
  const int rt = blockIdx.x;
  const int b = blockIdx.y;
  const int ch = blockIdx.z;
  #pragma unroll
  for (int k = 0; k < 4; k++) {
    int f = t + k * 256;
    int kr = f >> 4;
    int c = (f & 15) * 4;
    *(float4*)&Wl[kr][c] = *(const float4*)&W[kr * HD_ + ch * 64 + c];
  }
  #pragma unroll
  for (int k = 0; k < 2; k++) {
    int f = t + k * 256;
    int r = f >> 4;
    int c = (f & 15) * 4;
    int row = rt * 32 + r;
    float4 v = make_float4(0.f, 0.f, 0.f, 0.f);
    if (row < Nn) v = *(const float4*)&x[(b * Nn + row) * Dd + c];
    *(float4*)&xr[r][c] = v;
  }
  __syncthreads();
  const int tg = t >> 4;
  const int tc = t & 15;
  const int rb = tg * 2, c0 = tc * 4;
  float acc[2][4] = {};
  #pragma unroll
  for (int k4 = 0; k4 < 16; k4++) {
    float4 xv0 = *(float4*)&xr[rb][k4 * 4];
    float4 xv1 = *(float4*)&xr[rb + 1][k4 * 4];
    #pragma unroll
    for (int kk = 0; kk < 4; kk++) {
      float4 wv = *(float4*)&Wl[k4 * 4 + kk][c0];
      float xs0 = (&xv0.x)[kk];
      float xs1 = (&xv1.x)[kk];
      acc[0][0] = fmaf(xs0, wv.x, acc[0][0]);
      acc[0][1] = fmaf(xs0, wv.y, acc[0][1]);
      acc[0][2] = fmaf(xs0, wv.z, acc[0][2]);
      acc[0][3] = fmaf(xs0, wv.w, acc[0][3]);
      acc[1][0] = fmaf(xs1, wv.x, acc[1][0]);
      acc[1][1] = fmaf(xs1, wv.y, acc[1][1]);
      acc[1][2] = fmaf(xs1, wv.z, acc[1][2]);
      acc[1][3] = fmaf(xs1, wv.w, acc[1][3]);
    }
  }
  #pragma unroll
  for (int cc = 0; cc < 4; cc++) {
    #pragma unroll
    for (int r = 0; r < 2; r++) {
      st[(c0 + cc) * 33 + rb + r] = f2bf(acc[r][cc]);
    }
  }
  float w1v[4], w2v[4];
  #pragma unroll
  for (int cc = 0; cc < 4; cc++) {
    w1v[cc] = attw[ch * 128 + c0 + cc];
    w2v[cc] = attw[ch * 128 + 64 + c0 + cc];
  }
  #pragma unroll
  for (int r = 0; r < 2; r++) {
    float p1 = acc[r][0] * w1v[0] + acc[r][1] * w1v[1] +
               acc[r][2] * w1v[2] + acc[r][3] * w1v[3];
    float p2 = acc[r][0] * w2v[0] + acc[r][1] * w2v[1] +
               acc[r][2] * w2v[2] + acc[r][3] * w2v[3];
    #pragma unroll
    for (int off = 1; off <= 8; off <<= 1) {
      p1 += __shfl_xor(p1, off, 64);
      p2 += __shfl_xor(p2, off, 64);
    }
    if (tc == 0) {
      int row = rt * 32 + rb + r;
      if (row < Nn) {
        si[(b * 4 + ch) * Nn + row] = p1;
        sj[(b * 4 + ch) * Nn + row] = p2;
      }
    }
  }
  __syncthreads();
  if (t < 64) {
    unsigned short* dst = &xtT[((size_t)(b * 4 + ch) * 64 + t) * Kpad + rt * 32];
    #pragma unroll
    for (int q = 0; q < 4; q++) {
      short8 v;
      #pragma unroll
      for (int k = 0; k < 8; k++) v[k] = (short)st[t * 33 + q * 8 + k];
      *(short8*)&dst[q * 8] = v;
    }
  }
}

// K2a (round-8 verbatim, verified): causal-channel conv + bias, once.
__global__ __launch_bounds__(256) void k2a_cconv(const float* __restrict__ causal,
                                                 const float* __restrict__ convw,
                                                 const float* __restrict__ convb,
                                                 float* __restrict__ ccv) {
  const int i = blockIdx.x;
  const int t = threadIdx.x;
  #pragma unroll
  for (int qq = 0; qq < 2; qq++) {
    const int j = t + qq * 256;
    float tap[9];
    #pragma unroll
    for (int r3 = 0; r3 < 3; r3++) {
      int ii = i - 1 + r3;
      #pragma unroll
      for (int c3 = 0; c3 < 3; c3++) {
        int jj = j - 1 + c3;
        tap[r3 * 3 + c3] = (ii >= 0 && ii < Nn && jj >= 0 && jj < Nn)
                               ? causal[ii * Nn + jj] : 0.f;
      }
    }
    #pragma unroll
    for (int h = 0; h < 4; h++) {
      float acc = convb[h];
      #pragma unroll
      for (int q = 0; q < 9; q++) acc = fmaf(convw[h * 18 + 9 + q], tap[q], acc);
      ccv[((size_t)h * Nn + i) * 512 + j] = acc;
    }
  }
}

// K2 v5: SINGLE change vs the verified round-5/8 v2 — i-tile 8 -> 4 rows.
// am_t shrinks 10->6 rows: LDS 30.8 -> 22.1 KB => 7 blocks/CU (was 5),
// 28 waves/CU in flight (+40%) for this latency-bound kernel. Each wave
// owns ONE i-row x 4 heads. Every am element still computed once per
// block with identical op order; conv/softmax/A-write verbatim => A
// bitwise identical.
__global__ __launch_bounds__(256) void k2_attn(const float* __restrict__ si,
                                               const float* __restrict__ sj,
                                               const float* __restrict__ ccv,
                                               const float* __restrict__ convw,
                                               float* __restrict__ A) {
  __shared__ float am_t[6 * 8 * 68];    // rows r=0..5 (iq = i0 + r - 1)
  __shared__ float sjl[4 * 8 * 68];     // [h][e][c]
  __shared__ float sil[4][8];           // [h][r], r = 0..5
  __shared__ float cwl[4][9];           // am-channel conv weights
  const int t = threadIdx.x;
  const int i0 = blockIdx.x * 4;
  const int b = blockIdx.y;
  if (t < 36) cwl[t / 9][t % 9] = convw[(t / 9) * 18 + (t % 9)];
  if (t >= 40 && t < 64) {
    int q = t - 40;
    int h = q / 6, r = q % 6;
    int iq = i0 + r - 1;
    sil[h][r] = (iq >= 0 && iq < Nn) ? si[(b * 4 + h) * Nn + iq] : 0.f;
  }
  if (t >= 64 && t < 160) {
    int q = t - 64;
    int r = q >> 4, rem = q & 15;       // r = 0..5
    int e = rem >> 1, side = rem & 1;
    am_t[(r * 8 + e) * 68 + side * 65] = 0.f;
  }
  for (int f = t; f < 2048; f += 256) {
    int h = f >> 9, j = f & 511;
    float v = (j < Nn) ? sj[(b * 4 + h) * Nn + j] : 0.f;
    sjl[(h * 8 + (j & 7)) * 68 + (j >> 3) + 1] = v;
  }
  __syncthreads();
  for (int f = t; f < 3072; f += 256) {
    int r = f >> 9, j = f & 511;        // r = 0..5
    int iq = i0 + r - 1;
    float am = 0.f;
    if (iq >= 0 && iq < Nn && j < Nn) {
      float s = 0.f;
      #pragma unroll
      for (int h = 0; h < 4; h++) {
        float e2 = sil[h][r] + sjl[(h * 8 + (j & 7)) * 68 + (j >> 3) + 1];
        s += (e2 >= 0.f) ? e2 : SLOPE * e2;
      }
      am = 0.25f * s;
    }
    am_t[(r * 8 + (j & 7)) * 68 + (j >> 3) + 1] = am;
  }
  __syncthreads();
  const int w = t >> 6, L = t & 63;
  const int j0 = L * 8;
  const int il = w;                     // wave owns one i-row
  const int i = i0 + il;
  if (i >= Nn) return;                  // wave-uniform
  float conv[4][8];
  #pragma unroll
  for (int h = 0; h < 4; h++) {
    const float* cp = &ccv[((size_t)h * Nn + i) * 512 + j0];
    float4 c0 = *(const float4*)&cp[0];
    float4 c1 = *(const float4*)&cp[4];
    conv[h][0] = c0.x; conv[h][1] = c0.y; conv[h][2] = c0.z; conv[h][3] = c0.w;
    conv[h][4] = c1.x; conv[h][5] = c1.y; conv[h][6] = c1.z; conv[h][7] = c1.w;
  }
  #pragma unroll
  for (int r3 = 0; r3 < 3; r3++) {
    const float* ba = &am_t[((il + r3) * 8) * 68];
    float a[10];
    a[0] = ba[7 * 68 + L];
    #pragma unroll
    for (int e = 0; e < 8; e++) a[1 + e] = ba[e * 68 + L + 1];
    a[9] = ba[0 * 68 + L + 2];
    #pragma unroll
    for (int h = 0; h < 4; h++) {
      float w0 = cwl[h][r3 * 3], w1 = cwl[h][r3 * 3 + 1], w2 = cwl[h][r3 * 3 + 2];
      #pragma unroll
      for (int e = 0; e < 8; e++) {
        float cv = conv[h][e];
        cv = fmaf(w0, a[e], cv);
        cv = fmaf(w1, a[e + 1], cv);
        cv = fmaf(w2, a[e + 2], cv);
        conv[h][e] = cv;
      }
    }
  }
  #pragma unroll
  for (int h = 0; h < 4; h++) {
    const float sih = sil[h][il + 1];
    float v[8];
    float mx = NEG_INF;
    #pragma unroll
    for (int e = 0; e < 8; e++) {
      float ee = sih + sjl[(h * 8 + e) * 68 + L + 1];
      float l = (ee >= 0.f) ? ee : SLOPE * ee;
      float val = ALPHA_ * l + (1.0f - ALPHA_) * conv[h][e];
      v[e] = (j0 + e < Nn) ? val : NEG_INF;
      mx = fmaxf(mx, v[e]);
    }
    mx = wredmax(mx);
    float p[8], s = 0.f;
    #pragma unroll
    for (int e = 0; e < 8; e++) {
      p[e] = __expf(v[e] - mx);
      s += p[e];
    }
    s = wredsum(s);
    const float inv = 1.f / s;
    #pragma unroll
    for (int e = 0; e < 8; e++) p[e] *= inv;
    float* Ar = &A[((size_t)(b * 4 + h) * Nn + i) * Nn + j0];
    *(float4*)&Ar[0] = make_float4(p[0], p[1], p[2], p[3]);
    if (L < 63) {
      *(float4*)&Ar[4] = make_float4(p[4], p[5], p[6], p[7]);
    } else {
      *(float2*)&Ar[4] = make_float2(p[4], p[5]);
    }
  }
}

// K3 v4 (round-8 verbatim, verified): 3-buffer async-split pipeline.
__global__ __launch_bounds__(256) void k3_out(const float* __restrict__ A,
                                              const unsigned short* __restrict__ xtT,
                                              const float* __restrict__ x,
                                              const float* __restrict__ fcgw,
                                              const float* __restrict__ fcgb,
                                              const float* __restrict__ lng,
                                              const float* __restrict__ lnb,
                                              float* __restrict__ y) {
  __shared__ unsigned short Asub[3][16 * 72];
  __shared__ float ol[16][64];
  __shared__ float gl[2][128];
  const int t = threadIdx.x;
  const int n0 = blockIdx.x * 16;
  const int b = blockIdx.y;
  const int w = t >> 6, L = t & 63;
  const int quad = L >> 4, l16 = L & 15;
  const int wc = w * 16;
  const int ar = t >> 4;
  const int amc = (t & 15) * 4;
  const int nrow = n0 + ar;
  floatx4 acc = {0.f, 0.f, 0.f, 0.f};

  auto loadA = [&](int p, float* av) {
    const int h = p >> 3;
    const int m = (p & 7) * 64 + amc;
    av[0] = av[1] = av[2] = av[3] = 0.f;
    if (nrow < Nn) {
      const float* src = &A[((size_t)(b * 4 + h) * Nn + nrow) * Nn + m];
      if (m + 3 < Nn) {
        float2 v0 = *(const float2*)&src[0];
        float2 v1 = *(const float2*)&src[2];
        av[0] = v0.x; av[1] = v0.y; av[2] = v1.x; av[3] = v1.y;
      } else {
        int lim = Nn - m;
        #pragma unroll
        for (int q = 0; q < 4; q++) if (q < lim) av[q] = src[q];
      }
    }
  };
  auto writeA = [&](int p, const float* av) {
    ushort4 u;
    u.x = f2bf(av[0]); u.y = f2bf(av[1]);
    u.z = f2bf(av[2]); u.w = f2bf(av[3]);
    *(ushort4*)&Asub[p % 3][ar * 72 + amc] = u;
  };

  float rvA[4], rvB[4];
  loadA(0, rvA);
  loadA(1, rvB);
  writeA(0, rvA);
  __syncthreads();
  #pragma unroll
  for (int p = 0; p < 32; p++) {
    if (p + 2 < 32) loadA(p + 2, (p & 1) ? rvB : rvA);
    if (p + 1 < 32) writeA(p + 1, (p & 1) ? rvA : rvB);
    __syncthreads();
    const int h = p >> 3;
    const unsigned short* Xr =
        &xtT[((size_t)(b * 4 + h) * 64 + wc + l16) * Kpad + (p & 7) * 64];
    const unsigned short* Ab = &Asub[p % 3][l16 * 72];
    short8 af0 = *(const short8*)&Ab[quad * 8];
    short8 bf0 = *(const short8*)&Xr[quad * 8];
    acc = __builtin_amdgcn_mfma_f32_16x16x32_bf16(af0, bf0, acc, 0, 0, 0);
    short8 af1 = *(const short8*)&Ab[32 + quad * 8];
    short8 bf1 = *(const short8*)&Xr[32 + quad * 8];
    acc = __builtin_amdgcn_mfma_f32_16x16x32_bf16(af1, bf1, acc, 0, 0, 0);
  }

  __syncthreads();
  #pragma unroll
  for (int reg = 0; reg < 4; reg++) {
    ol[quad * 4 + reg][wc + l16] = 0.25f * acc[reg];
  }
  __syncthreads();
  const int kk = t & 127;
  const int rg = t >> 7;
  for (int it = 0; it < 8; it++) {
    const int r = it * 2 + rg;
    const int row = n0 + r;
    float g = fcgb[kk];
    #pragma unroll
    for (int d = 0; d < 64; d++) g = fmaf(ol[r][d], fcgw[d * 128 + kk], g);
    gl[rg][kk] = g;
    __syncthreads();
    if (kk < 64 && row < Nn) {
      float a = gl[rg][kk];
      float bb = gl[rg][kk + 64];
      float glu = a / (1.f + __expf(-bb));
      float yv = glu + x[(b * Nn + row) * Dd + kk];
      float mu = wredsum(yv) * (1.f / 64.f);
      float dv = yv - mu;
      float var = wredsum(dv * dv) * (1.f / 64.f);
      float o = dv * rsqrtf(var + LNEPS) * lng[kk] + lnb[kk];
      y[(b * Nn + row) * Dd + kk] = o;
    }
    __syncthreads();
  }
}

extern "C" void kernel_launch(void* const* d_in, const int* in_sizes, int n_in,
                              void* d_out, int out_size, void* d_ws, size_t ws_size,
                              hipStream_t stream) {
  const float* x      = (const float*)d_in[0];
  const float* causal = (const float*)d_in[1];
  const float* W      = (const float*)d_in[2];
  const float* attw   = (const float*)d_in[3];
  const float* convw  = (const float*)d_in[4];
  const float* convb  = (const float*)d_in[5];
  const float* fcgw   = (const float*)d_in[6];
  const float* fcgb   = (const float*)d_in[7];
  const float* lng    = (const float*)d_in[8];
  const float* lnb    = (const float*)d_in[9];

  float* ws = (float*)d_ws;
  float* si = ws;                                  // 65,280 floats
  float* sj = si + (size_t)Bz * Hh * Nn;           // 65,280 floats (+16 pad)
  unsigned short* xtT = (unsigned short*)(sj + (size_t)Bz * Hh * Nn + 16);
  // xtT: 32*4*64*512 shorts = 4,194,304 shorts (8.39 MB)
  float* ccv = (float*)(xtT + (size_t)Bz * Hh * Dd * Kpad);  // 4*510*512 floats

  float* yout = (float*)d_out;                     // 32*510*64
  float* Aout = yout + (size_t)Bz * Nn * Dd;       // 32*4*510*510

  k2a_cconv<<<dim3(Nn), 256, 0, stream>>>(causal, convw, convb, ccv);
  k1_xt  <<<dim3(16, Bz, 4), 256, 0, stream>>>(x, W, attw, xtT, si, sj);
  k2_attn<<<dim3(128, Bz), 256, 0, stream>>>(si, sj, ccv, convw, Aout);
  k3_out <<<dim3(32, Bz), 256, 0, stream>>>(Aout, xtT, x, fcgw, fcgb, lng, lnb, yout);
}

// Round 13
// 259.640 us; speedup vs baseline: 1.0927x; 1.0244x over previous
//
#include <hip/hip_runtime.h>

#define Bz 32
#define Nn 510
#define Dd 64
#define Hh 4
#define HD_ 256
#define Kpad 512
#define ALPHA_ 0.1f
#define LNEPS 1e-5f
#define SLOPE 0.01f
#define NEG_INF -3.0e38f

typedef __attribute__((ext_vector_type(8))) short short8;
typedef __attribute__((ext_vector_type(4))) float floatx4;

__device__ inline float wredsum(float v) {
  #pragma unroll
  for (int off = 32; off; off >>= 1) v += __shfl_xor(v, off, 64);
  return v;
}
__device__ inline float wredmax(float v) {
  #pragma unroll
  for (int off = 32; off; off >>= 1) v = fmaxf(v, __shfl_xor(v, off, 64));
  return v;
}
__device__ inline unsigned short f2bf(float f) {
  unsigned int u = __float_as_uint(f);
  unsigned int r = (u + 0x7fffu + ((u >> 16) & 1u)) >> 16;
  return (unsigned short)r;
}

// K1 v3 (verified): one head per block. LDS 30.3KB -> 5 blocks/CU.
__global__ __launch_bounds__(256) void k1_xt(const float* __restrict__ x,
                                             const float* __restrict__ W,
                                             const float* __restrict__ attw,
                                             unsigned short* __restrict__ xtT,
                                             float* __restrict__ si,
                                             float* __restrict__ sj) {
  __shared__ float Wl[64][68];
  __shared__ float xr[32][68];
  __shared__ unsigned short st[64 * 33];
  const int t = threadIdx.x;
  const int rt = blockIdx.x;
  const int b = blockIdx.y;
  const int ch = blockIdx.z;
  #pragma unroll
  for (int k = 0; k < 4; k++) {
    int f = t + k * 256;
    int kr = f >> 4;
    int c = (f & 15) * 4;
    *(float4*)&Wl[kr][c] = *(const float4*)&W[kr * HD_ + ch * 64 + c];
  }
  #pragma unroll
  for (int k = 0; k < 2; k++) {
    int f = t + k * 256;
    int r = f >> 4;
    int c = (f & 15) * 4;
    int row = rt * 32 + r;
    float4 v = make_float4(0.f, 0.f, 0.f, 0.f);
    if (row < Nn) v = *(const float4*)&x[(b * Nn + row) * Dd + c];
    *(float4*)&xr[r][c] = v;
  }
  __syncthreads();
  const int tg = t >> 4;
  const int tc = t & 15;
  const int rb = tg * 2, c0 = tc * 4;
  float acc[2][4] = {};
  #pragma unroll
  for (int k4 = 0; k4 < 16; k4++) {
    float4 xv0 = *(float4*)&xr[rb][k4 * 4];
    float4 xv1 = *(float4*)&xr[rb + 1][k4 * 4];
    #pragma unroll
    for (int kk = 0; kk < 4; kk++) {
      float4 wv = *(float4*)&Wl[k4 * 4 + kk][c0];
      float xs0 = (&xv0.x)[kk];
      float xs1 = (&xv1.x)[kk];
      acc[0][0] = fmaf(xs0, wv.x, acc[0][0]);
      acc[0][1] = fmaf(xs0, wv.y, acc[0][1]);
      acc[0][2] = fmaf(xs0, wv.z, acc[0][2]);
      acc[0][3] = fmaf(xs0, wv.w, acc[0][3]);
      acc[1][0] = fmaf(xs1, wv.x, acc[1][0]);
      acc[1][1] = fmaf(xs1, wv.y, acc[1][1]);
      acc[1][2] = fmaf(xs1, wv.z, acc[1][2]);
      acc[1][3] = fmaf(xs1, wv.w, acc[1][3]);
    }
  }
  #pragma unroll
  for (int cc = 0; cc < 4; cc++) {
    #pragma unroll
    for (int r = 0; r < 2; r++) {
      st[(c0 + cc) * 33 + rb + r] = f2bf(acc[r][cc]);
    }
  }
  float w1v[4], w2v[4];
  #pragma unroll
  for (int cc = 0; cc < 4; cc++) {
    w1v[cc] = attw[ch * 128 + c0 + cc];
    w2v[cc] = attw[ch * 128 + 64 + c0 + cc];
  }
  #pragma unroll
  for (int r = 0; r < 2; r++) {
    float p1 = acc[r][0] * w1v[0] + acc[r][1] * w1v[1] +
               acc[r][2] * w1v[2] + acc[r][3] * w1v[3];
    float p2 = acc[r][0] * w2v[0] + acc[r][1] * w2v[1] +
               acc[r][2] * w2v[2] + acc[r][3] * w2v[3];
    #pragma unroll
    for (int off = 1; off <= 8; off <<= 1) {
      p1 += __shfl_xor(p1, off, 64);
      p2 += __shfl_xor(p2, off, 64);
    }
    if (tc == 0) {
      int row = rt * 32 + rb + r;
      if (row < Nn) {
        si[(b * 4 + ch) * Nn + row] = p1;
        sj[(b * 4 + ch) * Nn + row] = p2;
      }
    }
  }
  __syncthreads();
  if (t < 64) {
    unsigned short* dst = &xtT[((size_t)(b * 4 + ch) * 64 + t) * Kpad + rt * 32];
    #pragma unroll
    for (int q = 0; q < 4; q++) {
      short8 v;
      #pragma unroll
      for (int k = 0; k < 8; k++) v[k] = (short)st[t * 33 + q * 8 + k];
      *(short8*)&dst[q * 8] = v;
    }
  }
}

// K2a (verified): causal-channel conv + bias, batch-independent, once.
__global__ __launch_bounds__(256) void k2a_cconv(const float* __restrict__ causal,
                                                 const float* __restrict__ convw,
                                                 const float* __restrict__ convb,
                                                 float* __restrict__ ccv) {
  const int i = blockIdx.x;
  const int t = threadIdx.x;
  #pragma unroll
  for (int qq = 0; qq < 2; qq++) {
    const int j = t + qq * 256;
    float tap[9];
    #pragma unroll
    for (int r3 = 0; r3 < 3; r3++) {
      int ii = i - 1 + r3;
      #pragma unroll
      for (int c3 = 0; c3 < 3; c3++) {
        int jj = j - 1 + c3;
        tap[r3 * 3 + c3] = (ii >= 0 && ii < Nn && jj >= 0 && jj < Nn)
                               ? causal[ii * Nn + jj] : 0.f;
      }
    }
    #pragma unroll
    for (int h = 0; h < 4; h++) {
      float acc = convb[h];
      #pragma unroll
      for (int q = 0; q < 9; q++) acc = fmaf(convw[h * 18 + 9 + q], tap[q], acc);
      ccv[((size_t)h * Nn + i) * 512 + j] = acc;
    }
  }
}

// K2 v2 (verified best): LDS am staging (each am element computed once per
// block), causal conv from ccv, wave owns 2 i-rows x all 4 heads.
__global__ __launch_bounds__(256) void k2_attn(const float* __restrict__ si,
                                               const float* __restrict__ sj,
                                               const float* __restrict__ ccv,
                                               const float* __restrict__ convw,
                                               float* __restrict__ A) {
  __shared__ float am_t[10 * 8 * 68];   // [row r][e=j&7][c=(j>>3)+1]
  __shared__ float sjl[4 * 8 * 68];     // [h][e][c]
  __shared__ float sil[4][12];
  __shared__ float cwl[4][9];           // am-channel conv weights
  const int t = threadIdx.x;
  const int i0 = blockIdx.x * 8;
  const int b = blockIdx.y;
  if (t < 36) cwl[t / 9][t % 9] = convw[(t / 9) * 18 + (t % 9)];
  if (t < 40) {
    int h = t / 10, r = t % 10;
    int iq = i0 + r - 1;
    sil[h][r] = (iq >= 0 && iq < Nn) ? si[(b * 4 + h) * Nn + iq] : 0.f;
  }
  if (t >= 64 && t < 224) {
    int q = t - 64;
    int r = q >> 4, rem = q & 15;
    int e = rem >> 1, side = rem & 1;
    am_t[(r * 8 + e) * 68 + side * 65] = 0.f;
  }
  for (int f = t; f < 2048; f += 256) {
    int h = f >> 9, j = f & 511;
    float v = (j < Nn) ? sj[(b * 4 + h) * Nn + j] : 0.f;
    sjl[(h * 8 + (j & 7)) * 68 + (j >> 3) + 1] = v;
  }
  __syncthreads();
  for (int f = t; f < 5120; f += 256) {
    int r = f >> 9, j = f & 511;
    int iq = i0 + r - 1;
    float am = 0.f;
    if (iq >= 0 && iq < Nn && j < Nn) {
      float s = 0.f;
      #pragma unroll
      for (int h = 0; h < 4; h++) {
        float e2 = sil[h][r] + sjl[(h * 8 + (j & 7)) * 68 + (j >> 3) + 1];
        s += (e2 >= 0.f) ? e2 : SLOPE * e2;
      }
      am = 0.25f * s;
    }
    am_t[(r * 8 + (j & 7)) * 68 + (j >> 3) + 1] = am;
  }
  __syncthreads();
  const int w = t >> 6, L = t & 63;
  const int j0 = L * 8;
  #pragma unroll
  for (int qq = 0; qq < 2; qq++) {
    const int il = w * 2 + qq;
    const int i = i0 + il;
    if (i >= Nn) continue;
    float conv[4][8];
    #pragma unroll
    for (int h = 0; h < 4; h++) {
      const float* cp = &ccv[((size_t)h * Nn + i) * 512 + j0];
      float4 c0 = *(const float4*)&cp[0];
      float4 c1 = *(const float4*)&cp[4];
      conv[h][0] = c0.x; conv[h][1] = c0.y; conv[h][2] = c0.z; conv[h][3] = c0.w;
      conv[h][4] = c1.x; conv[h][5] = c1.y; conv[h][6] = c1.z; conv[h][7] = c1.w;
    }
    #pragma unroll
    for (int r3 = 0; r3 < 3; r3++) {
      const float* ba = &am_t[((il + r3) * 8) * 68];
      float a[10];
      a[0] = ba[7 * 68 + L];
      #pragma unroll
      for (int e = 0; e < 8; e++) a[1 + e] = ba[e * 68 + L + 1];
      a[9] = ba[0 * 68 + L + 2];
      #pragma unroll
      for (int h = 0; h < 4; h++) {
        float w0 = cwl[h][r3 * 3], w1 = cwl[h][r3 * 3 + 1], w2 = cwl[h][r3 * 3 + 2];
        #pragma unroll
        for (int e = 0; e < 8; e++) {
          float cv = conv[h][e];
          cv = fmaf(w0, a[e], cv);
          cv = fmaf(w1, a[e + 1], cv);
          cv = fmaf(w2, a[e + 2], cv);
          conv[h][e] = cv;
        }
      }
    }
    #pragma unroll
    for (int h = 0; h < 4; h++) {
      const float sih = sil[h][il + 1];
      float v[8];
      float mx = NEG_INF;
      #pragma unroll
      for (int e = 0; e < 8; e++) {
        float ee = sih + sjl[(h * 8 + e) * 68 + L + 1];
        float l = (ee >= 0.f) ? ee : SLOPE * ee;
        float val = ALPHA_ * l + (1.0f - ALPHA_) * conv[h][e];
        v[e] = (j0 + e < Nn) ? val : NEG_INF;
        mx = fmaxf(mx, v[e]);
      }
      mx = wredmax(mx);
      float p[8], s = 0.f;
      #pragma unroll
      for (int e = 0; e < 8; e++) {
        p[e] = __expf(v[e] - mx);
        s += p[e];
      }
      s = wredsum(s);
      const float inv = 1.f / s;
      #pragma unroll
      for (int e = 0; e < 8; e++) p[e] *= inv;
      float* Ar = &A[((size_t)(b * 4 + h) * Nn + i) * Nn + j0];
      *(float4*)&Ar[0] = make_float4(p[0], p[1], p[2], p[3]);
      if (L < 63) {
        *(float4*)&Ar[4] = make_float4(p[4], p[5], p[6], p[7]);
      } else {
        *(float2*)&Ar[4] = make_float2(p[4], p[5]);
      }
    }
  }
}

// K3 v4 (verified): 3-buffer async-split pipeline, X direct from global.
__global__ __launch_bounds__(256) void k3_out(const float* __restrict__ A,
                                              const unsigned short* __restrict__ xtT,
                                              const float* __restrict__ x,
                                              const float* __restrict__ fcgw,
                                              const float* __restrict__ fcgb,
                                              const float* __restrict__ lng,
                                              const float* __restrict__ lnb,
                                              float* __restrict__ y) {
  __shared__ unsigned short Asub[3][16 * 72];
  __shared__ float ol[16][64];
  __shared__ float gl[2][128];
  const int t = threadIdx.x;
  const int n0 = blockIdx.x * 16;
  const int b = blockIdx.y;
  const int w = t >> 6, L = t & 63;
  const int quad = L >> 4, l16 = L & 15;
  const int wc = w * 16;
  const int ar = t >> 4;
  const int amc = (t & 15) * 4;
  const int nrow = n0 + ar;
  floatx4 acc = {0.f, 0.f, 0.f, 0.f};

  auto loadA = [&](int p, float* av) {
    const int h = p >> 3;
    const int m = (p & 7) * 64 + amc;
    av[0] = av[1] = av[2] = av[3] = 0.f;
    if (nrow < Nn) {
      const float* src = &A[((size_t)(b * 4 + h) * Nn + nrow) * Nn + m];
      if (m + 3 < Nn) {
        float2 v0 = *(const float2*)&src[0];
        float2 v1 = *(const float2*)&src[2];
        av[0] = v0.x; av[1] = v0.y; av[2] = v1.x; av[3] = v1.y;
      } else {
        int lim = Nn - m;
        #pragma unroll
        for (int q = 0; q < 4; q++) if (q < lim) av[q] = src[q];
      }
    }
  };
  auto writeA = [&](int p, const float* av) {
    ushort4 u;
    u.x = f2bf(av[0]); u.y = f2bf(av[1]);
    u.z = f2bf(av[2]); u.w = f2bf(av[3]);
    *(ushort4*)&Asub[p % 3][ar * 72 + amc] = u;
  };

  float rvA[4], rvB[4];
  loadA(0, rvA);
  loadA(1, rvB);
  writeA(0, rvA);
  __syncthreads();
  #pragma unroll
  for (int p = 0; p < 32; p++) {
    if (p + 2 < 32) loadA(p + 2, (p & 1) ? rvB : rvA);
    if (p + 1 < 32) writeA(p + 1, (p & 1) ? rvA : rvB);
    __syncthreads();
    const int h = p >> 3;
    const unsigned short* Xr =
        &xtT[((size_t)(b * 4 + h) * 64 + wc + l16) * Kpad + (p & 7) * 64];
    const unsigned short* Ab = &Asub[p % 3][l16 * 72];
    short8 af0 = *(const short8*)&Ab[quad * 8];
    short8 bf0 = *(const short8*)&Xr[quad * 8];
    acc = __builtin_amdgcn_mfma_f32_16x16x32_bf16(af0, bf0, acc, 0, 0, 0);
    short8 af1 = *(const short8*)&Ab[32 + quad * 8];
    short8 bf1 = *(const short8*)&Xr[32 + quad * 8];
    acc = __builtin_amdgcn_mfma_f32_16x16x32_bf16(af1, bf1, acc, 0, 0, 0);
  }

  __syncthreads();
  #pragma unroll
  for (int reg = 0; reg < 4; reg++) {
    ol[quad * 4 + reg][wc + l16] = 0.25f * acc[reg];
  }
  __syncthreads();
  const int kk = t & 127;
  const int rg = t >> 7;
  for (int it = 0; it < 8; it++) {
    const int r = it * 2 + rg;
    const int row = n0 + r;
    float g = fcgb[kk];
    #pragma unroll
    for (int d = 0; d < 64; d++) g = fmaf(ol[r][d], fcgw[d * 128 + kk], g);
    gl[rg][kk] = g;
    __syncthreads();
    if (kk < 64 && row < Nn) {
      float a = gl[rg][kk];
      float bb = gl[rg][kk + 64];
      float glu = a / (1.f + __expf(-bb));
      float yv = glu + x[(b * Nn + row) * Dd + kk];
      float mu = wredsum(yv) * (1.f / 64.f);
      float dv = yv - mu;
      float var = wredsum(dv * dv) * (1.f / 64.f);
      float o = dv * rsqrtf(var + LNEPS) * lng[kk] + lnb[kk];
      y[(b * Nn + row) * Dd + kk] = o;
    }
    __syncthreads();
  }
}

extern "C" void kernel_launch(void* const* d_in, const int* in_sizes, int n_in,
                              void* d_out, int out_size, void* d_ws, size_t ws_size,
                              hipStream_t stream) {
  const float* x      = (const float*)d_in[0];
  const float* causal = (const float*)d_in[1];
  const float* W      = (const float*)d_in[2];
  const float* attw   = (const float*)d_in[3];
  const float* convw  = (const float*)d_in[4];
  const float* convb  = (const float*)d_in[5];
  const float* fcgw   = (const float*)d_in[6];
  const float* fcgb   = (const float*)d_in[7];
  const float* lng    = (const float*)d_in[8];
  const float* lnb    = (const float*)d_in[9];

  float* ws = (float*)d_ws;
  float* si = ws;                                  // 65,280 floats
  float* sj = si + (size_t)Bz * Hh * Nn;           // 65,280 floats (+16 pad)
  unsigned short* xtT = (unsigned short*)(sj + (size_t)Bz * Hh * Nn + 16);
  // xtT: 32*4*64*512 shorts = 4,194,304 shorts (8.39 MB)
  float* ccv = (float*)(xtT + (size_t)Bz * Hh * Dd * Kpad);  // 4*510*512 floats

  float* yout = (float*)d_out;                     // 32*510*64
  float* Aout = yout + (size_t)Bz * Nn * Dd;       // 32*4*510*510

  k2a_cconv<<<dim3(Nn), 256, 0, stream>>>(causal, convw, convb, ccv);
  k1_xt  <<<dim3(16, Bz, 4), 256, 0, stream>>>(x, W, attw, xtT, si, sj);
  k2_attn<<<dim3(64, Bz), 256, 0, stream>>>(si, sj, ccv, convw, Aout);
  k3_out <<<dim3(32, Bz), 256, 0, stream>>>(Aout, xtT, x, fcgw, fcgb, lng, lnb, yout);
}